// Round 2
// baseline (1629.312 us; speedup 1.0000x reference)
//
#include <hip/hip_runtime.h>
#include <cstddef>

constexpr int   kN  = 1024;
constexpr int   kE  = 16384;
constexpr int   kQ  = 8192;
constexpr int   kH  = 32;
constexpr size_t kNN = (size_t)kN * kN;
constexpr float kEPS = 1e-5f;

// ---------------- small graph kernels ----------------

__global__ void k_edge(const int* __restrict__ ei, float* __restrict__ deg,
                       unsigned char* __restrict__ adj) {
    int e = blockIdx.x * 256 + threadIdx.x;
    if (e < kE) {
        int s = ei[e], d = ei[kE + e];
        atomicAdd(&deg[d], 1.0f);
        adj[s * kN + d] = 1;   // duplicate edges write the same value: fine
    }
}

__global__ void k_dinv(const float* __restrict__ deg, float* __restrict__ dinv) {
    int n = blockIdx.x * 256 + threadIdx.x;
    if (n < kN) dinv[n] = rsqrtf(deg[n] + 1.0f);
}

__global__ void k_embed(const int* __restrict__ xids, const float* __restrict__ emb,
                        float* __restrict__ x0) {
    int t = blockIdx.x * 256 + threadIdx.x;  // kN*kH threads
    int n = t >> 5, c = t & 31;
    x0[t] = emb[xids[n] * kH + c];
}

// h = x @ W   (kN x 32) @ (32 x 32)
__global__ void k_node_mm(const float* __restrict__ x, const float* __restrict__ W,
                          float* __restrict__ h) {
    __shared__ float Ws[kH * kH];
    int t = threadIdx.x;
    for (int u = t; u < kH * kH; u += 256) Ws[u] = W[u];
    __syncthreads();
    int g = blockIdx.x * 256 + t;
    int n = g >> 5, c = g & 31;
    float acc = 0.f;
#pragma unroll
    for (int d = 0; d < kH; d++) acc = fmaf(x[n * kH + d], Ws[d * kH + c], acc);
    h[g] = acc;
}

// agg[dst] += h[src] * dinv[src]*dinv[dst]
__global__ void k_scatter(const int* __restrict__ ei, const float* __restrict__ h,
                          const float* __restrict__ dinv, float* __restrict__ agg) {
    int t = blockIdx.x * 256 + threadIdx.x;  // kE*kH threads
    int e = t >> 5, c = t & 31;
    int s = ei[e], d = ei[kE + e];
    atomicAdd(&agg[d * kH + c], h[s * kH + c] * dinv[s] * dinv[d]);
}

__global__ void k_gcn_post(float* __restrict__ agg, const float* __restrict__ h,
                           const float* __restrict__ dinv, const float* __restrict__ b) {
    int t = blockIdx.x * 256 + threadIdx.x;  // kN*kH
    int n = t >> 5, c = t & 31;
    agg[t] += h[t] * dinv[n] * dinv[n] + b[c];
}

// graphnorm over nodes (per channel), then relu. One block per channel.
__global__ void k_graphnorm(const float* __restrict__ x, float* __restrict__ out,
                            const float* __restrict__ g, const float* __restrict__ b,
                            const float* __restrict__ a, int M) {
    int c = blockIdx.x, t = threadIdx.x;
    float s = 0.f, ss = 0.f;
    for (int m = t; m < M; m += 256) { float v = x[m * kH + c]; s += v; ss += v * v; }
    __shared__ float rs[256], rss[256];
    rs[t] = s; rss[t] = ss;
    __syncthreads();
    for (int o = 128; o > 0; o >>= 1) {
        if (t < o) { rs[t] += rs[t + o]; rss[t] += rss[t + o]; }
        __syncthreads();
    }
    __shared__ float scale, shift;
    if (t == 0) {
        float mu  = rs[0] / (float)M;
        float ac  = a[c];
        float var = rss[0] / (float)M - 2.f * ac * mu * mu + ac * ac * mu * mu;
        float sc  = g[c] * rsqrtf(var + kEPS);
        scale = sc;
        shift = b[c] - sc * ac * mu;
    }
    __syncthreads();
    for (int m = t; m < M; m += 256) {
        float v = scale * x[m * kH + c] + shift;
        out[m * kH + c] = v > 0.f ? v : 0.f;
    }
}

// ---------------- x1/x2 generation for a chunk of CW channels, channel-major (c,i,j) ----------------

template<int CW>
__global__ __launch_bounds__(256) void k_genx12(
        const float* __restrict__ xn, const unsigned char* __restrict__ adj,
        const float* __restrict__ w1, const float* __restrict__ b1,
        const float* __restrict__ w2, const float* __restrict__ b2,
        float* __restrict__ X1c, float* __restrict__ X2c, int c0) {
    __shared__ float W1s[33 * CW], W2s[33 * CW];
    __shared__ float b1s[CW], b2s[CW], xi[kH];
    __shared__ float xjs[256][kH + 1];
    int i = blockIdx.y, j0 = blockIdx.x * 256, t = threadIdx.x;
    for (int u = t; u < 33 * CW; u += 256) {
        int d = u / CW, cc = u % CW;
        W1s[u] = w1[d * kH + c0 + cc];
        W2s[u] = w2[d * kH + c0 + cc];
    }
    if (t < CW) { b1s[t] = b1[c0 + t]; b2s[t] = b2[c0 + t]; }
    if (t < kH) xi[t] = xn[i * kH + t];
    for (int u = t; u < 256 * kH; u += 256) {
        xjs[u >> 5][u & 31] = xn[(j0 + (u >> 5)) * kH + (u & 31)];
    }
    __syncthreads();
    int j = j0 + t;
    float p[kH];
#pragma unroll
    for (int d = 0; d < kH; d++) p[d] = xi[d] * xjs[t][d];
    float e = (float)adj[i * kN + j];
#pragma unroll
    for (int cc = 0; cc < CW; cc++) {
        float v1 = b1s[cc], v2 = b2s[cc];
#pragma unroll
        for (int d = 0; d < kH; d++) {
            v1 = fmaf(p[d], W1s[d * CW + cc], v1);
            v2 = fmaf(p[d], W2s[d * CW + cc], v2);
        }
        v1 = fmaf(e, W1s[32 * CW + cc], v1);
        v2 = fmaf(e, W2s[32 * CW + cc], v2);
        X1c[(size_t)cc * kNN + (size_t)i * kN + j] = v1 > 0.f ? v1 : 0.f;
        X2c[(size_t)cc * kNN + (size_t)i * kN + j] = v2 > 0.f ? v2 : 0.f;
    }
}

// ---------------- batched fp32 SGEMM: prod[c] = X1[c] @ X2[c], per-channel 1024^3 ----------------

__global__ __launch_bounds__(256) void k_bgemm(const float* __restrict__ A_,
                                               const float* __restrict__ B_,
                                               float* __restrict__ C_) {
    int c = blockIdx.z;
    const float* A = A_ + (size_t)c * kNN;
    const float* B = B_ + (size_t)c * kNN;
    float*       C = C_ + (size_t)c * kNN;
    int i0 = blockIdx.y * 128, j0 = blockIdx.x * 128;
    __shared__ float As[8][128];
    __shared__ float Bs[8][128];
    int t = threadIdx.x, tx = t & 15, ty = t >> 4;
    float acc[2][2][4][4] = {};
    for (int k0 = 0; k0 < kN; k0 += 8) {
        {   // A tile: 128 rows x 8 k, stored k-major (transposed into LDS)
            int row = t >> 1, kq = t & 1;
            float4 av = *(const float4*)&A[(size_t)(i0 + row) * kN + k0 + 4 * kq];
            As[4 * kq + 0][row] = av.x; As[4 * kq + 1][row] = av.y;
            As[4 * kq + 2][row] = av.z; As[4 * kq + 3][row] = av.w;
            // B tile: 8 k-rows x 128 cols
            int kk = t >> 5, cq = t & 31;
            float4 bv = *(const float4*)&B[(size_t)(k0 + kk) * kN + j0 + 4 * cq];
            *(float4*)&Bs[kk][4 * cq] = bv;
        }
        __syncthreads();
#pragma unroll
        for (int kk = 0; kk < 8; kk++) {
            float4 A0 = *(const float4*)&As[kk][ty * 4];
            float4 A1 = *(const float4*)&As[kk][64 + ty * 4];
            float4 B0 = *(const float4*)&Bs[kk][tx * 4];
            float4 B1 = *(const float4*)&Bs[kk][64 + tx * 4];
            float a[2][4] = {{A0.x, A0.y, A0.z, A0.w}, {A1.x, A1.y, A1.z, A1.w}};
            float b[2][4] = {{B0.x, B0.y, B0.z, B0.w}, {B1.x, B1.y, B1.z, B1.w}};
#pragma unroll
            for (int rh = 0; rh < 2; rh++)
#pragma unroll
                for (int ch = 0; ch < 2; ch++)
#pragma unroll
                    for (int r = 0; r < 4; r++)
#pragma unroll
                        for (int cl = 0; cl < 4; cl++)
                            acc[rh][ch][r][cl] = fmaf(a[rh][r], b[ch][cl], acc[rh][ch][r][cl]);
        }
        __syncthreads();
    }
#pragma unroll
    for (int rh = 0; rh < 2; rh++)
#pragma unroll
        for (int r = 0; r < 4; r++) {
            int row = i0 + rh * 64 + ty * 4 + r;
#pragma unroll
            for (int ch = 0; ch < 2; ch++) {
                float4 v = make_float4(acc[rh][ch][r][0], acc[rh][ch][r][1],
                                       acc[rh][ch][r][2], acc[rh][ch][r][3]);
                *(float4*)&C[(size_t)row * kN + j0 + ch * 64 + tx * 4] = v;
            }
        }
}

// ---------------- gn3 statistics: reduce sum/sumsq of y over all (i,k), y never stored ----------------

__global__ __launch_bounds__(256) void k_stats(
        const float* __restrict__ xn, const unsigned char* __restrict__ adj,
        const float* __restrict__ prod, const float* __restrict__ w3,
        const float* __restrict__ b3, float* __restrict__ stats) {
    __shared__ float W3s[65 * kH], b3s[kH], xi[kH];
    __shared__ float lsum[kH], lssq[kH];
    int i = blockIdx.y, k0 = blockIdx.x * 256, t = threadIdx.x;
    for (int u = t; u < 65 * kH; u += 256) W3s[u] = w3[u];
    if (t < kH) { b3s[t] = b3[t]; xi[t] = xn[i * kH + t]; lsum[t] = 0.f; lssq[t] = 0.f; }
    __syncthreads();
    int k = k0 + t;
    float p[kH], pr[kH];
#pragma unroll
    for (int d = 0; d < kH; d++) p[d] = xi[d] * xn[k * kH + d];
    float e = (float)adj[i * kN + k];
#pragma unroll
    for (int d = 0; d < kH; d++) pr[d] = prod[(size_t)d * kNN + (size_t)i * kN + k];
    for (int c = 0; c < kH; c++) {
        float v = b3s[c];
#pragma unroll
        for (int d = 0; d < kH; d++) v = fmaf(p[d], W3s[d * kH + c], v);
        v = fmaf(e, W3s[32 * kH + c], v);
#pragma unroll
        for (int d = 0; d < kH; d++) v = fmaf(pr[d], W3s[(33 + d) * kH + c], v);
        float s = v, q2 = v * v;
#pragma unroll
        for (int o = 32; o > 0; o >>= 1) { s += __shfl_down(s, o); q2 += __shfl_down(q2, o); }
        if ((t & 63) == 0) { atomicAdd(&lsum[c], s); atomicAdd(&lssq[c], q2); }
    }
    __syncthreads();
    if (t < kH) { atomicAdd(&stats[t], lsum[t]); atomicAdd(&stats[kH + t], lssq[t]); }
}

__global__ void k_finalize(const float* __restrict__ stats, const float* __restrict__ g,
                           const float* __restrict__ b, const float* __restrict__ a,
                           float* __restrict__ ss) {
    int c = threadIdx.x;  // 32 threads
    float M   = (float)((double)kNN);
    float mu  = stats[c] / M;
    float ac  = a[c];
    float var = stats[kH + c] / M - 2.f * ac * mu * mu + ac * ac * mu * mu;
    float sc  = g[c] * rsqrtf(var + kEPS);
    ss[c]      = sc;
    ss[kH + c] = b[c] - sc * ac * mu;
}

// ---------------- final: recompute y at (i,k) and (k,i), symmetrize, project ----------------

__global__ __launch_bounds__(256) void k_out(
        const int* __restrict__ pos, const float* __restrict__ xn,
        const unsigned char* __restrict__ adj, const float* __restrict__ prod,
        const float* __restrict__ w3, const float* __restrict__ b3,
        const float* __restrict__ ss, const float* __restrict__ wdir,
        const float* __restrict__ bdir, float* __restrict__ out) {
    __shared__ float W3s[65 * kH], b3s[kH], scs[kH], shs[kH], wd[kH];
    int t = threadIdx.x;
    for (int u = t; u < 65 * kH; u += 256) W3s[u] = w3[u];
    if (t < kH) { b3s[t] = b3[t]; scs[t] = ss[t]; shs[t] = ss[kH + t]; wd[t] = wdir[t]; }
    __syncthreads();
    int q = blockIdx.x * 256 + t;
    int i = pos[2 * q], k = pos[2 * q + 1];
    float p[kH], pr1[kH], pr2[kH];
#pragma unroll
    for (int d = 0; d < kH; d++) p[d] = xn[i * kH + d] * xn[k * kH + d];
#pragma unroll
    for (int d = 0; d < kH; d++) {
        pr1[d] = prod[(size_t)d * kNN + (size_t)i * kN + k];
        pr2[d] = prod[(size_t)d * kNN + (size_t)k * kN + i];
    }
    float e1 = (float)adj[i * kN + k], e2 = (float)adj[k * kN + i];
    float acc = bdir[0];
    for (int c = 0; c < kH; c++) {
        float y1 = b3s[c], y2 = b3s[c];
#pragma unroll
        for (int d = 0; d < kH; d++) {
            float w = W3s[d * kH + c];
            y1 = fmaf(p[d], w, y1); y2 = fmaf(p[d], w, y2);
        }
        y1 = fmaf(e1, W3s[32 * kH + c], y1);
        y2 = fmaf(e2, W3s[32 * kH + c], y2);
#pragma unroll
        for (int d = 0; d < kH; d++) {
            float w = W3s[(33 + d) * kH + c];
            y1 = fmaf(pr1[d], w, y1); y2 = fmaf(pr2[d], w, y2);
        }
        float z1 = scs[c] * y1 + shs[c]; z1 = z1 > 0.f ? z1 : 0.f;
        float z2 = scs[c] * y2 + shs[c]; z2 = z2 > 0.f ? z2 : 0.f;
        acc = fmaf(z1 * z2, wd[c], acc);
    }
    out[q] = acc;
}

// ---------------- launch ----------------

template<int CW>
static void run_chunks(const float* xb, const unsigned char* adj,
                       const float* wm1, const float* bm1,
                       const float* wm2, const float* bm2,
                       float* X1c, float* X2c, float* prod, hipStream_t stream) {
    for (int c0 = 0; c0 < kH; c0 += CW) {
        k_genx12<CW><<<dim3(4, kN), 256, 0, stream>>>(xb, adj, wm1, bm1, wm2, bm2,
                                                      X1c, X2c, c0);
        k_bgemm<<<dim3(8, 8, CW), 256, 0, stream>>>(X1c, X2c, prod + (size_t)c0 * kNN);
    }
}

extern "C" void kernel_launch(void* const* d_in, const int* in_sizes, int n_in,
                              void* d_out, int out_size, void* d_ws, size_t ws_size,
                              hipStream_t stream) {
    const int*   x_ids = (const int*)d_in[0];
    const int*   ei    = (const int*)d_in[1];
    const int*   pos   = (const int*)d_in[2];
    const float* emb   = (const float*)d_in[3];
    const float* gw0   = (const float*)d_in[4];
    const float* gb0   = (const float*)d_in[5];
    const float* g0g   = (const float*)d_in[6];
    const float* g0b   = (const float*)d_in[7];
    const float* g0a   = (const float*)d_in[8];
    const float* gw1   = (const float*)d_in[9];
    const float* gb1   = (const float*)d_in[10];
    const float* g1g   = (const float*)d_in[11];
    const float* g1b   = (const float*)d_in[12];
    const float* g1a   = (const float*)d_in[13];
    const float* wm1   = (const float*)d_in[14];
    const float* bm1   = (const float*)d_in[15];
    const float* wm2   = (const float*)d_in[16];
    const float* bm2   = (const float*)d_in[17];
    const float* wm3   = (const float*)d_in[18];
    const float* bm3   = (const float*)d_in[19];
    const float* g3g   = (const float*)d_in[20];
    const float* g3b   = (const float*)d_in[21];
    const float* g3a   = (const float*)d_in[22];
    const float* wdir  = (const float*)d_in[23];
    const float* bdir  = (const float*)d_in[24];
    float* out = (float*)d_out;

    // pick channel-chunk width CW so that prod(128MB) + 2*CW*4MB + ~2MB fits ws_size
    const size_t fixedF = kH * kNN;            // prod floats
    const size_t tailB  = kNN + (1 << 20);     // adj bytes + node buffers slack
    int CW = 1;
    if (ws_size >= (fixedF + 2 * 8 * kNN) * 4 + tailB)      CW = 8;
    else if (ws_size >= (fixedF + 2 * 2 * kNN) * 4 + tailB) CW = 2;

    // workspace layout
    float* prod = (float*)d_ws;                       // 128 MB
    float* X1c  = prod + fixedF;                      // CW*4MB
    float* X2c  = X1c + (size_t)CW * kNN;             // CW*4MB
    unsigned char* adj = (unsigned char*)(X2c + (size_t)CW * kNN);  // 1 MB
    float* deg   = (float*)(adj + kNN);
    float* dinv  = deg + kN;
    float* x0    = dinv + kN;
    float* h     = x0 + kN * kH;
    float* agg   = h + kN * kH;
    float* xa    = agg + kN * kH;
    float* xb    = xa + kN * kH;
    float* stats = xb + kN * kH;
    float* ss    = stats + 2 * kH;

    hipMemsetAsync(deg, 0, kN * sizeof(float), stream);
    hipMemsetAsync(adj, 0, kNN, stream);
    hipMemsetAsync(stats, 0, 2 * kH * sizeof(float), stream);
    hipMemsetAsync(agg, 0, kN * kH * sizeof(float), stream);

    k_edge<<<(kE + 255) / 256, 256, 0, stream>>>(ei, deg, adj);
    k_dinv<<<4, 256, 0, stream>>>(deg, dinv);
    k_embed<<<kN * kH / 256, 256, 0, stream>>>(x_ids, emb, x0);

    // GCN layer 0
    k_node_mm<<<kN * kH / 256, 256, 0, stream>>>(x0, gw0, h);
    k_scatter<<<kE * kH / 256, 256, 0, stream>>>(ei, h, dinv, agg);
    k_gcn_post<<<kN * kH / 256, 256, 0, stream>>>(agg, h, dinv, gb0);
    k_graphnorm<<<kH, 256, 0, stream>>>(agg, xa, g0g, g0b, g0a, kN);

    // GCN layer 1
    hipMemsetAsync(agg, 0, kN * kH * sizeof(float), stream);
    k_node_mm<<<kN * kH / 256, 256, 0, stream>>>(xa, gw1, h);
    k_scatter<<<kE * kH / 256, 256, 0, stream>>>(ei, h, dinv, agg);
    k_gcn_post<<<kN * kH / 256, 256, 0, stream>>>(agg, h, dinv, gb1);
    k_graphnorm<<<kH, 256, 0, stream>>>(agg, xb, g1g, g1b, g1a, kN);

    // pairwise MLP features + batched per-channel GEMMs, streamed in channel chunks
    if (CW == 8)      run_chunks<8>(xb, adj, wm1, bm1, wm2, bm2, X1c, X2c, prod, stream);
    else if (CW == 2) run_chunks<2>(xb, adj, wm1, bm1, wm2, bm2, X1c, X2c, prod, stream);
    else              run_chunks<1>(xb, adj, wm1, bm1, wm2, bm2, X1c, X2c, prod, stream);

    // gn3 stats without materializing y
    k_stats<<<dim3(4, kN), 256, 0, stream>>>(xb, adj, prod, wm3, bm3, stats);
    k_finalize<<<1, 32, 0, stream>>>(stats, g3g, g3b, g3a, ss);

    // final gather + symmetric product + projection
    k_out<<<kQ / 256, 256, 0, stream>>>(pos, xb, adj, prod, wm3, bm3, ss, wdir, bdir, out);
}

// Round 3
// 749.400 us; speedup vs baseline: 2.1742x; 2.1742x over previous
//
#include <hip/hip_runtime.h>
#include <hip/hip_bf16.h>
#include <cstddef>

constexpr int   kN  = 1024;
constexpr int   kE  = 16384;
constexpr int   kQ  = 8192;
constexpr int   kH  = 32;
constexpr size_t kNN = (size_t)kN * kN;
constexpr float kEPS = 1e-5f;

using short8 = __attribute__((ext_vector_type(8))) short;
using f32x4  = __attribute__((ext_vector_type(4))) float;

// ---------------- small graph kernels ----------------

__global__ void k_edge(const int* __restrict__ ei, float* __restrict__ deg,
                       unsigned char* __restrict__ adj, unsigned char* __restrict__ adjT) {
    int e = blockIdx.x * 256 + threadIdx.x;
    if (e < kE) {
        int s = ei[e], d = ei[kE + e];
        atomicAdd(&deg[d], 1.0f);
        adj [s * kN + d] = 1;   // eim[s][d]
        adjT[d * kN + s] = 1;   // eim^T
    }
}

__global__ void k_dinv(const float* __restrict__ deg, float* __restrict__ dinv) {
    int n = blockIdx.x * 256 + threadIdx.x;
    if (n < kN) dinv[n] = rsqrtf(deg[n] + 1.0f);
}

__global__ void k_embed(const int* __restrict__ xids, const float* __restrict__ emb,
                        float* __restrict__ x0) {
    int t = blockIdx.x * 256 + threadIdx.x;  // kN*kH threads
    int n = t >> 5, c = t & 31;
    x0[t] = emb[xids[n] * kH + c];
}

// h = x @ W   (kN x 32) @ (32 x 32)
__global__ void k_node_mm(const float* __restrict__ x, const float* __restrict__ W,
                          float* __restrict__ h) {
    __shared__ float Ws[kH * kH];
    int t = threadIdx.x;
    for (int u = t; u < kH * kH; u += 256) Ws[u] = W[u];
    __syncthreads();
    int g = blockIdx.x * 256 + t;
    int n = g >> 5, c = g & 31;
    float acc = 0.f;
#pragma unroll
    for (int d = 0; d < kH; d++) acc = fmaf(x[n * kH + d], Ws[d * kH + c], acc);
    h[g] = acc;
}

__global__ void k_scatter(const int* __restrict__ ei, const float* __restrict__ h,
                          const float* __restrict__ dinv, float* __restrict__ agg) {
    int t = blockIdx.x * 256 + threadIdx.x;  // kE*kH threads
    int e = t >> 5, c = t & 31;
    int s = ei[e], d = ei[kE + e];
    atomicAdd(&agg[d * kH + c], h[s * kH + c] * dinv[s] * dinv[d]);
}

__global__ void k_gcn_post(float* __restrict__ agg, const float* __restrict__ h,
                           const float* __restrict__ dinv, const float* __restrict__ b) {
    int t = blockIdx.x * 256 + threadIdx.x;  // kN*kH
    int n = t >> 5, c = t & 31;
    agg[t] += h[t] * dinv[n] * dinv[n] + b[c];
}

// graphnorm over nodes (per channel), then relu. One block per channel.
__global__ void k_graphnorm(const float* __restrict__ x, float* __restrict__ out,
                            const float* __restrict__ g, const float* __restrict__ b,
                            const float* __restrict__ a, int M) {
    int c = blockIdx.x, t = threadIdx.x;
    float s = 0.f, ss = 0.f;
    for (int m = t; m < M; m += 256) { float v = x[m * kH + c]; s += v; ss += v * v; }
    __shared__ float rs[256], rss[256];
    rs[t] = s; rss[t] = ss;
    __syncthreads();
    for (int o = 128; o > 0; o >>= 1) {
        if (t < o) { rs[t] += rs[t + o]; rss[t] += rss[t + o]; }
        __syncthreads();
    }
    __shared__ float scale, shift;
    if (t == 0) {
        float mu  = rs[0] / (float)M;
        float ac  = a[c];
        float var = rss[0] / (float)M - 2.f * ac * mu * mu + ac * ac * mu * mu;
        float sc  = g[c] * rsqrtf(var + kEPS);
        scale = sc;
        shift = b[c] - sc * ac * mu;
    }
    __syncthreads();
    for (int m = t; m < M; m += 256) {
        float v = scale * x[m * kH + c] + shift;
        out[m * kH + c] = v > 0.f ? v : 0.f;
    }
}

// ---------------- x1 / x2^T generation (bf16, channel-major) ----------------
// X[cc][o][in] = relu( W·(xn[o] ⊙ xn[in]) + adjX[o][in]·W_e + b ), bf16.
// For X1: o=i, in=j, adjX=adj.  For X2^T: o=j, in=k, adjX=adj^T (pair product is symmetric).

template<int CW>
__global__ __launch_bounds__(256) void k_genx(
        const float* __restrict__ xn, const unsigned char* __restrict__ adjX,
        const float* __restrict__ w, const float* __restrict__ b,
        __hip_bfloat16* __restrict__ X, int c0) {
    __shared__ float Ws[33 * CW], bs[CW], xo[kH];
    __shared__ float xis[256][kH + 1];
    int o = blockIdx.y, i0 = blockIdx.x * 256, t = threadIdx.x;
    for (int u = t; u < 33 * CW; u += 256) {
        int d = u / CW, cc = u % CW;
        Ws[u] = w[d * kH + c0 + cc];
    }
    if (t < CW) bs[t] = b[c0 + t];
    if (t < kH) xo[t] = xn[o * kH + t];
    for (int u = t; u < 256 * kH; u += 256) {
        xis[u >> 5][u & 31] = xn[(i0 + (u >> 5)) * kH + (u & 31)];
    }
    __syncthreads();
    int in = i0 + t;
    float p[kH];
#pragma unroll
    for (int d = 0; d < kH; d++) p[d] = xo[d] * xis[t][d];
    float e = (float)adjX[o * kN + in];
#pragma unroll
    for (int cc = 0; cc < CW; cc++) {
        float v = bs[cc];
#pragma unroll
        for (int d = 0; d < kH; d++) v = fmaf(p[d], Ws[d * CW + cc], v);
        v = fmaf(e, Ws[32 * CW + cc], v);
        X[(size_t)cc * kNN + (size_t)o * kN + in] = __float2bfloat16(v > 0.f ? v : 0.f);
    }
}

// ---------------- bf16 MFMA batched GEMM: C[c] = A[c] @ B[c], B given transposed ----------------
// A: [c][1024][1024] bf16 row-major (M x K). Bt: [c][1024][1024] bf16 (N x K). C fp32.
// 128x128 tile, 4 waves (2x2), each wave 64x64 = 4x4 frags of 16x16, K-step 32 (m97 structure).

__device__ __forceinline__ void g2l16(const unsigned short* g, unsigned short* l) {
    __builtin_amdgcn_global_load_lds(
        (const __attribute__((address_space(1))) void*)g,
        (__attribute__((address_space(3))) void*)l, 16, 0, 0);
}

__global__ __launch_bounds__(256) void k_bgemm_bf16(
        const unsigned short* __restrict__ A_, const unsigned short* __restrict__ Bt_,
        float* __restrict__ C_) {
    int c = blockIdx.z;
    const unsigned short* A  = A_  + (size_t)c * kNN;
    const unsigned short* Bt = Bt_ + (size_t)c * kNN;
    float* C = C_ + (size_t)c * kNN;
    int i0 = blockIdx.y * 128, j0 = blockIdx.x * 128;
    __shared__ unsigned short As[128 * 32];
    __shared__ unsigned short Bs[128 * 32];
    int t = threadIdx.x;
    int lane = t & 63, w = t >> 6;
    int wr = (w >> 1) * 64, wc = (w & 1) * 64;
    int l15 = lane & 15, lhi = lane >> 4;  // 0..3
    // staging addressing: LDS chunk q (16B) = tile row q>>2, k-elems (q&3)*8
    int srow = t >> 2, skel = (t & 3) * 8;
    f32x4 acc[4][4] = {};
    for (int k0 = 0; k0 < kN; k0 += 32) {
        g2l16(A  + (size_t)(i0 + srow)      * kN + k0 + skel, As + (size_t)t * 8);
        g2l16(A  + (size_t)(i0 + srow + 64) * kN + k0 + skel, As + (size_t)(t + 256) * 8);
        g2l16(Bt + (size_t)(j0 + srow)      * kN + k0 + skel, Bs + (size_t)t * 8);
        g2l16(Bt + (size_t)(j0 + srow + 64) * kN + k0 + skel, Bs + (size_t)(t + 256) * 8);
        asm volatile("s_waitcnt vmcnt(0)" ::: "memory");
        __syncthreads();
        short8 af[4], bf[4];
#pragma unroll
        for (int m = 0; m < 4; m++)
            af[m] = *(const short8*)&As[(wr + m * 16 + l15) * 32 + lhi * 8];
#pragma unroll
        for (int n = 0; n < 4; n++)
            bf[n] = *(const short8*)&Bs[(wc + n * 16 + l15) * 32 + lhi * 8];
#pragma unroll
        for (int m = 0; m < 4; m++)
#pragma unroll
            for (int n = 0; n < 4; n++)
                acc[m][n] = __builtin_amdgcn_mfma_f32_16x16x32_bf16(af[m], bf[n], acc[m][n], 0, 0, 0);
        __syncthreads();
    }
    // C/D layout: col = lane&15, row = (lane>>4)*4 + r   [m89-verified]
#pragma unroll
    for (int m = 0; m < 4; m++) {
        int row = i0 + wr + m * 16 + lhi * 4;
#pragma unroll
        for (int n = 0; n < 4; n++) {
            int col = j0 + wc + n * 16 + l15;
#pragma unroll
            for (int r = 0; r < 4; r++)
                C[(size_t)(row + r) * kN + col] = acc[m][n][r];
        }
    }
}

// ---------------- gn3 statistics: reduce sum/sumsq of y over all (i,k), y never stored ----------------

__global__ __launch_bounds__(256) void k_stats(
        const float* __restrict__ xn, const unsigned char* __restrict__ adj,
        const float* __restrict__ prod, const float* __restrict__ w3,
        const float* __restrict__ b3, float* __restrict__ stats) {
    __shared__ float W3s[65 * kH], b3s[kH], xi[kH];
    __shared__ float lsum[kH], lssq[kH];
    int i = blockIdx.y, k0 = blockIdx.x * 256, t = threadIdx.x;
    for (int u = t; u < 65 * kH; u += 256) W3s[u] = w3[u];
    if (t < kH) { b3s[t] = b3[t]; xi[t] = xn[i * kH + t]; lsum[t] = 0.f; lssq[t] = 0.f; }
    __syncthreads();
    int k = k0 + t;
    float p[kH], pr[kH];
#pragma unroll
    for (int d = 0; d < kH; d++) p[d] = xi[d] * xn[k * kH + d];
    float e = (float)adj[i * kN + k];
#pragma unroll
    for (int d = 0; d < kH; d++) pr[d] = prod[(size_t)d * kNN + (size_t)i * kN + k];
    for (int c = 0; c < kH; c++) {
        float v = b3s[c];
#pragma unroll
        for (int d = 0; d < kH; d++) v = fmaf(p[d], W3s[d * kH + c], v);
        v = fmaf(e, W3s[32 * kH + c], v);
#pragma unroll
        for (int d = 0; d < kH; d++) v = fmaf(pr[d], W3s[(33 + d) * kH + c], v);
        float s = v, q2 = v * v;
#pragma unroll
        for (int o = 32; o > 0; o >>= 1) { s += __shfl_down(s, o); q2 += __shfl_down(q2, o); }
        if ((t & 63) == 0) { atomicAdd(&lsum[c], s); atomicAdd(&lssq[c], q2); }
    }
    __syncthreads();
    if (t < kH) { atomicAdd(&stats[t], lsum[t]); atomicAdd(&stats[kH + t], lssq[t]); }
}

__global__ void k_finalize(const float* __restrict__ stats, const float* __restrict__ g,
                           const float* __restrict__ b, const float* __restrict__ a,
                           float* __restrict__ ss) {
    int c = threadIdx.x;  // 32 threads
    float M   = (float)((double)kNN);
    float mu  = stats[c] / M;
    float ac  = a[c];
    float var = stats[kH + c] / M - 2.f * ac * mu * mu + ac * ac * mu * mu;
    float sc  = g[c] * rsqrtf(var + kEPS);
    ss[c]      = sc;
    ss[kH + c] = b[c] - sc * ac * mu;
}

// ---------------- final: recompute y at (i,k) and (k,i), symmetrize, project ----------------

__global__ __launch_bounds__(256) void k_out(
        const int* __restrict__ pos, const float* __restrict__ xn,
        const unsigned char* __restrict__ adj, const float* __restrict__ prod,
        const float* __restrict__ w3, const float* __restrict__ b3,
        const float* __restrict__ ss, const float* __restrict__ wdir,
        const float* __restrict__ bdir, float* __restrict__ out) {
    __shared__ float W3s[65 * kH], b3s[kH], scs[kH], shs[kH], wd[kH];
    int t = threadIdx.x;
    for (int u = t; u < 65 * kH; u += 256) W3s[u] = w3[u];
    if (t < kH) { b3s[t] = b3[t]; scs[t] = ss[t]; shs[t] = ss[kH + t]; wd[t] = wdir[t]; }
    __syncthreads();
    int q = blockIdx.x * 256 + t;
    int i = pos[2 * q], k = pos[2 * q + 1];
    float p[kH], pr1[kH], pr2[kH];
#pragma unroll
    for (int d = 0; d < kH; d++) p[d] = xn[i * kH + d] * xn[k * kH + d];
#pragma unroll
    for (int d = 0; d < kH; d++) {
        pr1[d] = prod[(size_t)d * kNN + (size_t)i * kN + k];
        pr2[d] = prod[(size_t)d * kNN + (size_t)k * kN + i];
    }
    float e1 = (float)adj[i * kN + k], e2 = (float)adj[k * kN + i];
    float acc = bdir[0];
    for (int c = 0; c < kH; c++) {
        float y1 = b3s[c], y2 = b3s[c];
#pragma unroll
        for (int d = 0; d < kH; d++) {
            float w = W3s[d * kH + c];
            y1 = fmaf(p[d], w, y1); y2 = fmaf(p[d], w, y2);
        }
        y1 = fmaf(e1, W3s[32 * kH + c], y1);
        y2 = fmaf(e2, W3s[32 * kH + c], y2);
#pragma unroll
        for (int d = 0; d < kH; d++) {
            float w = W3s[(33 + d) * kH + c];
            y1 = fmaf(pr1[d], w, y1); y2 = fmaf(pr2[d], w, y2);
        }
        float z1 = scs[c] * y1 + shs[c]; z1 = z1 > 0.f ? z1 : 0.f;
        float z2 = scs[c] * y2 + shs[c]; z2 = z2 > 0.f ? z2 : 0.f;
        acc = fmaf(z1 * z2, wd[c], acc);
    }
    out[q] = acc;
}

// ---------------- launch ----------------

template<int CW>
static void run_chunks(const float* xb, const unsigned char* adj, const unsigned char* adjT,
                       const float* wm1, const float* bm1,
                       const float* wm2, const float* bm2,
                       unsigned short* X1c, unsigned short* X2c, float* prod,
                       hipStream_t stream) {
    for (int c0 = 0; c0 < kH; c0 += CW) {
        k_genx<CW><<<dim3(4, kN), 256, 0, stream>>>(xb, adj,  wm1, bm1,
                                                    (__hip_bfloat16*)X1c, c0);
        k_genx<CW><<<dim3(4, kN), 256, 0, stream>>>(xb, adjT, wm2, bm2,
                                                    (__hip_bfloat16*)X2c, c0);
        k_bgemm_bf16<<<dim3(8, 8, CW), 256, 0, stream>>>(X1c, X2c, prod + (size_t)c0 * kNN);
    }
}

extern "C" void kernel_launch(void* const* d_in, const int* in_sizes, int n_in,
                              void* d_out, int out_size, void* d_ws, size_t ws_size,
                              hipStream_t stream) {
    const int*   x_ids = (const int*)d_in[0];
    const int*   ei    = (const int*)d_in[1];
    const int*   pos   = (const int*)d_in[2];
    const float* emb   = (const float*)d_in[3];
    const float* gw0   = (const float*)d_in[4];
    const float* gb0   = (const float*)d_in[5];
    const float* g0g   = (const float*)d_in[6];
    const float* g0b   = (const float*)d_in[7];
    const float* g0a   = (const float*)d_in[8];
    const float* gw1   = (const float*)d_in[9];
    const float* gb1   = (const float*)d_in[10];
    const float* g1g   = (const float*)d_in[11];
    const float* g1b   = (const float*)d_in[12];
    const float* g1a   = (const float*)d_in[13];
    const float* wm1   = (const float*)d_in[14];
    const float* bm1   = (const float*)d_in[15];
    const float* wm2   = (const float*)d_in[16];
    const float* bm2   = (const float*)d_in[17];
    const float* wm3   = (const float*)d_in[18];
    const float* bm3   = (const float*)d_in[19];
    const float* g3g   = (const float*)d_in[20];
    const float* g3b   = (const float*)d_in[21];
    const float* g3a   = (const float*)d_in[22];
    const float* wdir  = (const float*)d_in[23];
    const float* bdir  = (const float*)d_in[24];
    float* out = (float*)d_out;

    // pick channel-chunk width CW: prod(128MB fp32) + 2*CW*2MB bf16 + adj/adjT + slack
    const size_t fixedF = (size_t)kH * kNN;           // prod floats
    const size_t tailB  = 2 * kNN + (1 << 20);        // adj + adjT + node buffers slack
    int CW = 1;
    if (ws_size >= fixedF * 4 + 2 * 8 * kNN * 2 + tailB)      CW = 8;
    else if (ws_size >= fixedF * 4 + 2 * 2 * kNN * 2 + tailB) CW = 2;

    // workspace layout
    float* prod = (float*)d_ws;                                   // 128 MB
    unsigned short* X1c = (unsigned short*)(prod + fixedF);       // CW*2MB bf16
    unsigned short* X2c = X1c + (size_t)CW * kNN;                 // CW*2MB bf16 (transposed)
    unsigned char* adj  = (unsigned char*)(X2c + (size_t)CW * kNN);  // 1 MB
    unsigned char* adjT = adj + kNN;                                  // 1 MB
    float* deg   = (float*)(adjT + kNN);
    float* dinv  = deg + kN;
    float* x0    = dinv + kN;
    float* h     = x0 + kN * kH;
    float* agg   = h + kN * kH;
    float* xa    = agg + kN * kH;
    float* xb    = xa + kN * kH;
    float* stats = xb + kN * kH;
    float* ss    = stats + 2 * kH;

    hipMemsetAsync(deg, 0, kN * sizeof(float), stream);
    hipMemsetAsync(adj, 0, 2 * kNN, stream);   // adj + adjT contiguous
    hipMemsetAsync(stats, 0, 2 * kH * sizeof(float), stream);
    hipMemsetAsync(agg, 0, kN * kH * sizeof(float), stream);

    k_edge<<<(kE + 255) / 256, 256, 0, stream>>>(ei, deg, adj, adjT);
    k_dinv<<<4, 256, 0, stream>>>(deg, dinv);
    k_embed<<<kN * kH / 256, 256, 0, stream>>>(x_ids, emb, x0);

    // GCN layer 0
    k_node_mm<<<kN * kH / 256, 256, 0, stream>>>(x0, gw0, h);
    k_scatter<<<kE * kH / 256, 256, 0, stream>>>(ei, h, dinv, agg);
    k_gcn_post<<<kN * kH / 256, 256, 0, stream>>>(agg, h, dinv, gb0);
    k_graphnorm<<<kH, 256, 0, stream>>>(agg, xa, g0g, g0b, g0a, kN);

    // GCN layer 1
    hipMemsetAsync(agg, 0, kN * kH * sizeof(float), stream);
    k_node_mm<<<kN * kH / 256, 256, 0, stream>>>(xa, gw1, h);
    k_scatter<<<kE * kH / 256, 256, 0, stream>>>(ei, h, dinv, agg);
    k_gcn_post<<<kN * kH / 256, 256, 0, stream>>>(agg, h, dinv, gb1);
    k_graphnorm<<<kH, 256, 0, stream>>>(agg, xb, g1g, g1b, g1a, kN);

    // pairwise bf16 features + batched per-channel MFMA GEMMs, streamed in channel chunks
    if (CW == 8)      run_chunks<8>(xb, adj, adjT, wm1, bm1, wm2, bm2, X1c, X2c, prod, stream);
    else if (CW == 2) run_chunks<2>(xb, adj, adjT, wm1, bm1, wm2, bm2, X1c, X2c, prod, stream);
    else              run_chunks<1>(xb, adj, adjT, wm1, bm1, wm2, bm2, X1c, X2c, prod, stream);

    // gn3 stats without materializing y
    k_stats<<<dim3(4, kN), 256, 0, stream>>>(xb, adj, prod, wm3, bm3, stats);
    k_finalize<<<1, 32, 0, stream>>>(stats, g3g, g3b, g3a, ss);

    // final gather + symmetric product + projection
    k_out<<<kQ / 256, 256, 0, stream>>>(pos, xb, adj, prod, wm3, bm3, ss, wdir, bdir, out);
}